// Round 1
// baseline (1487.647 us; speedup 1.0000x reference)
//
#include <hip/hip_runtime.h>

#define NN 50000
#define NE 400000
#define NG 32
#define SLOPE 0.2f

__device__ __forceinline__ unsigned enc_f(float f) {
    unsigned b = __float_as_uint(f);
    return (b & 0x80000000u) ? ~b : (b | 0x80000000u);
}
__device__ __forceinline__ float dec_f(unsigned u) {
    unsigned b = (u & 0x80000000u) ? (u & 0x7fffffffu) : ~u;
    return __uint_as_float(b);
}
__device__ __forceinline__ float lrelu(float v) { return v > 0.f ? v : SLOPE * v; }

// ---------------- NNConv: fused EdgeMLP(3->128->64->512) + einsum + scatter ----------------
// One thread per edge. h2[64] staged in LDS (transposed layout: h2s[k*128+t]) so the
// runtime-k einsum loop reads LDS (conflict-free, lanes consecutive) instead of
// runtime-indexing a register array (which would spill to scratch).
__global__ __launch_bounds__(128) void k_edge(
    const float* __restrict__ x, const float* __restrict__ ea,
    const int* __restrict__ src, const int* __restrict__ dst,
    const float* __restrict__ w1, const float* __restrict__ b1,
    const float* __restrict__ w2, const float* __restrict__ b2,
    const float* __restrict__ w3, const float* __restrict__ b3,
    float* __restrict__ agg)
{
    __shared__ float h2s[64 * 128];
    const int t = threadIdx.x;
    const int e = blockIdx.x * 128 + t;
    if (e >= NE) return;

    const float ea0 = ea[e * 3 + 0], ea1 = ea[e * 3 + 1], ea2 = ea[e * 3 + 2];

    float acc[64];
#pragma unroll
    for (int o = 0; o < 64; ++o) acc[o] = b2[o];

#pragma unroll 2
    for (int j = 0; j < 128; ++j) {
        float hj = fmaf(ea0, w1[j], fmaf(ea1, w1[128 + j], fmaf(ea2, w1[256 + j], b1[j])));
        hj = fmaxf(hj, 0.f);
        const float* __restrict__ w2r = w2 + j * 64;
#pragma unroll
        for (int o = 0; o < 64; ++o) acc[o] = fmaf(hj, w2r[o], acc[o]);
    }
#pragma unroll
    for (int o = 0; o < 64; ++o) h2s[o * 128 + t] = fmaxf(acc[o], 0.f);

    const int s = src[e], d = dst[e];
    float xs[16];
#pragma unroll
    for (int i = 0; i < 16; ++i) xs[i] = x[(size_t)s * 16 + i];

    float msg[32];
#pragma unroll
    for (int o = 0; o < 32; ++o) msg[o] = 0.f;
    // bias b3 contribution: msg[o] += sum_i xs[i]*b3[i*32+o]
#pragma unroll
    for (int i = 0; i < 16; ++i) {
        const float p = xs[i];
        const float* __restrict__ b3r = b3 + i * 32;
#pragma unroll
        for (int o = 0; o < 32; ++o) msg[o] = fmaf(p, b3r[o], msg[o]);
    }
    // main: msg[o] += sum_k h2[k] * sum_i xs[i] * w3[k, i*32+o]
    for (int k = 0; k < 64; ++k) {
        const float hk = h2s[k * 128 + t];
        const float* __restrict__ w3r = w3 + k * 512;
#pragma unroll
        for (int i = 0; i < 16; ++i) {
            const float p = hk * xs[i];
#pragma unroll
            for (int o = 0; o < 32; ++o) msg[o] = fmaf(p, w3r[i * 32 + o], msg[o]);
        }
    }
    float* aggd = agg + (size_t)d * 32;
#pragma unroll
    for (int o = 0; o < 32; ++o) atomicAdd(&aggd[o], msg[o]);
}

// h1 = relu(x @ root_w + agg + conv1_b), in-place on agg buffer
__global__ __launch_bounds__(256) void k_root(
    const float* __restrict__ x, const float* __restrict__ rw,
    const float* __restrict__ cb, float* __restrict__ h1)
{
    const int n = blockIdx.x * 256 + threadIdx.x;
    if (n >= NN) return;
    float acc[32];
#pragma unroll
    for (int o = 0; o < 32; ++o) acc[o] = cb[o] + h1[(size_t)n * 32 + o];
#pragma unroll
    for (int i = 0; i < 16; ++i) {
        const float xi = x[(size_t)n * 16 + i];
        const float* __restrict__ rwr = rw + i * 32;
#pragma unroll
        for (int o = 0; o < 32; ++o) acc[o] = fmaf(xi, rwr[o], acc[o]);
    }
#pragma unroll
    for (int o = 0; o < 32; ++o) h1[(size_t)n * 32 + o] = fmaxf(acc[o], 0.f);
}

// ---------------- GAT ----------------
// h = hin @ W; as = h.a_src; ad = h.a_dst; self-loop logit (leaky) seeds the running max.
template <int FI>
__global__ __launch_bounds__(256) void k_gat_h(
    const float* __restrict__ hin, const float* __restrict__ W,
    const float* __restrict__ av_s, const float* __restrict__ av_d,
    float* __restrict__ h, float* __restrict__ as_v, float* __restrict__ ad_v,
    unsigned* __restrict__ m_enc, float* __restrict__ sl)
{
    const int n = blockIdx.x * 256 + threadIdx.x;
    if (n >= NN) return;
    float acc[64];
#pragma unroll
    for (int o = 0; o < 64; ++o) acc[o] = 0.f;
#pragma unroll 2
    for (int i = 0; i < FI; ++i) {
        const float xi = hin[(size_t)n * FI + i];
        const float* __restrict__ wr = W + i * 64;
#pragma unroll
        for (int o = 0; o < 64; ++o) acc[o] = fmaf(xi, wr[o], acc[o]);
    }
    float s = 0.f, d = 0.f;
#pragma unroll
    for (int o = 0; o < 64; ++o) {
        h[(size_t)n * 64 + o] = acc[o];
        s = fmaf(acc[o], av_s[o], s);
        d = fmaf(acc[o], av_d[o], d);
    }
    as_v[n] = s;
    ad_v[n] = d;
    const float l = lrelu(s + d);
    sl[n] = l;
    m_enc[n] = enc_f(l);
}

__global__ __launch_bounds__(256) void k_gat_max(
    const int* __restrict__ src, const int* __restrict__ dst,
    const float* __restrict__ as_v, const float* __restrict__ ad_v,
    unsigned* __restrict__ m_enc)
{
    const int e = blockIdx.x * 256 + threadIdx.x;
    if (e >= NE) return;
    const float l = lrelu(as_v[src[e]] + ad_v[dst[e]]);
    atomicMax(&m_enc[dst[e]], enc_f(l));
}

// decode max; seed denom and acc with the self-loop contribution
__global__ __launch_bounds__(256) void k_gat_self(
    const unsigned* __restrict__ m_enc, const float* __restrict__ sl,
    const float* __restrict__ h, float* __restrict__ m_f,
    float* __restrict__ denom, float* __restrict__ acc)
{
    const int idx = blockIdx.x * 256 + threadIdx.x;
    if (idx >= NN * 64) return;
    const int n = idx >> 6, f = idx & 63;
    const float m = dec_f(m_enc[n]);
    const float w = expf(sl[n] - m);
    if (f == 0) { m_f[n] = m; denom[n] = w; }
    acc[idx] = w * h[idx];
}

__global__ __launch_bounds__(256) void k_gat_expsum(
    const int* __restrict__ src, const int* __restrict__ dst,
    const float* __restrict__ as_v, const float* __restrict__ ad_v,
    const float* __restrict__ m_f, float* __restrict__ ew, float* __restrict__ denom)
{
    const int e = blockIdx.x * 256 + threadIdx.x;
    if (e >= NE) return;
    const int d = dst[e];
    const float l = lrelu(as_v[src[e]] + ad_v[d]);
    const float w = expf(l - m_f[d]);
    ew[e] = w;
    atomicAdd(&denom[d], w);
}

// one wave per edge: 64 lanes = 64 features
__global__ __launch_bounds__(256) void k_gat_scatter(
    const int* __restrict__ src, const int* __restrict__ dst,
    const float* __restrict__ ew, const float* __restrict__ h, float* __restrict__ acc)
{
    const long long idx = (long long)blockIdx.x * 256 + threadIdx.x;
    const long long e = idx >> 6;
    if (e >= NE) return;
    const int f = (int)(idx & 63);
    const int s = src[e], d = dst[e];
    atomicAdd(&acc[(size_t)d * 64 + f], ew[e] * h[(size_t)s * 64 + f]);
}

__global__ __launch_bounds__(256) void k_gat_final(
    const float* __restrict__ acc, const float* __restrict__ denom,
    const float* __restrict__ b, float* __restrict__ out)
{
    const int idx = blockIdx.x * 256 + threadIdx.x;
    if (idx >= NN * 64) return;
    const float v = acc[idx] / denom[idx >> 6] + b[idx & 63];
    out[idx] = fmaxf(v, 0.f);
}

// ---------------- global mean pool (batch is sorted) ----------------
__global__ __launch_bounds__(256) void k_pool1(
    const float* __restrict__ h, const int* __restrict__ batch,
    float* __restrict__ gsum, float* __restrict__ gcnt)
{
    __shared__ float ls[NG * 64];
    __shared__ float lc[NG];
    for (int j = threadIdx.x; j < NG * 64; j += 256) ls[j] = 0.f;
    if (threadIdx.x < NG) lc[threadIdx.x] = 0.f;
    __syncthreads();
    const int base = blockIdx.x * 512;
    for (int idx = threadIdx.x; idx < 512 * 64; idx += 256) {
        const int nl = idx >> 6, f = idx & 63;
        const int n = base + nl;
        if (n < NN) {
            const int g = batch[n];
            atomicAdd(&ls[g * 64 + f], h[(size_t)n * 64 + f]);
            if (f == 0) atomicAdd(&lc[g], 1.f);
        }
    }
    __syncthreads();
    for (int j = threadIdx.x; j < NG * 64; j += 256) atomicAdd(&gsum[j], ls[j]);
    if (threadIdx.x < NG) atomicAdd(&gcnt[threadIdx.x], lc[threadIdx.x]);
}

__global__ __launch_bounds__(256) void k_pool2(
    const float* __restrict__ gsum, const float* __restrict__ gcnt, float* __restrict__ out)
{
    const int idx = blockIdx.x * 256 + threadIdx.x;
    if (idx >= NG * 64) return;
    out[idx] = gsum[idx] / fmaxf(gcnt[idx >> 6], 1.f);
}

extern "C" void kernel_launch(void* const* d_in, const int* in_sizes, int n_in,
                              void* d_out, int out_size, void* d_ws, size_t ws_size,
                              hipStream_t stream)
{
    const float* x     = (const float*)d_in[0];
    const float* ea    = (const float*)d_in[1];
    const int*   ei    = (const int*)d_in[2];
    const int*   batch = (const int*)d_in[3];
    const float* w1 = (const float*)d_in[4];   const float* b1 = (const float*)d_in[5];
    const float* w2 = (const float*)d_in[6];   const float* b2 = (const float*)d_in[7];
    const float* w3 = (const float*)d_in[8];   const float* b3 = (const float*)d_in[9];
    const float* rw = (const float*)d_in[10];  const float* cb = (const float*)d_in[11];
    const float* g1w  = (const float*)d_in[12]; const float* g1as = (const float*)d_in[13];
    const float* g1ad = (const float*)d_in[14]; const float* g1b  = (const float*)d_in[15];
    const float* g2w  = (const float*)d_in[16]; const float* g2as = (const float*)d_in[17];
    const float* g2ad = (const float*)d_in[18]; const float* g2b  = (const float*)d_in[19];
    const int* src = ei;
    const int* dst = ei + NE;
    float* out = (float*)d_out;

    char* ws = (char*)d_ws;
    size_t off = 0;
    auto alloc = [&](size_t bytes) -> char* {
        char* p = ws + off;
        off += (bytes + 255) & ~(size_t)255;
        return p;
    };
    float*    hA    = (float*)alloc((size_t)NN * 32 * 4);  // agg -> h1 (in place)
    float*    hB    = (float*)alloc((size_t)NN * 64 * 4);  // transformed h per GAT layer
    float*    hC    = (float*)alloc((size_t)NN * 64 * 4);  // GAT1 acc -> h2 (in place)
    float*    hD    = (float*)alloc((size_t)NN * 64 * 4);  // GAT2 acc -> h3 (in place)
    float*    as_v  = (float*)alloc((size_t)NN * 4);
    float*    ad_v  = (float*)alloc((size_t)NN * 4);
    unsigned* m_enc = (unsigned*)alloc((size_t)NN * 4);
    float*    sl    = (float*)alloc((size_t)NN * 4);
    float*    m_f   = (float*)alloc((size_t)NN * 4);
    float*    denom = (float*)alloc((size_t)NN * 4);
    float*    ew    = (float*)alloc((size_t)NE * 4);
    float*    gsum  = (float*)alloc((size_t)NG * 64 * 4);
    float*    gcnt  = (float*)alloc((size_t)NG * 4);
    (void)ws_size; (void)in_sizes; (void)n_in; (void)out_size;

    hipMemsetAsync(hA, 0, (size_t)NN * 32 * 4, stream);
    hipMemsetAsync(gsum, 0, (size_t)NG * 64 * 4, stream);
    hipMemsetAsync(gcnt, 0, (size_t)NG * 4, stream);

    // NNConv
    k_edge<<<(NE + 127) / 128, 128, 0, stream>>>(x, ea, src, dst, w1, b1, w2, b2, w3, b3, hA);
    k_root<<<(NN + 255) / 256, 256, 0, stream>>>(x, rw, cb, hA);

    // GAT layer 1: hA [N,32] -> hC [N,64]
    k_gat_h<32><<<(NN + 255) / 256, 256, 0, stream>>>(hA, g1w, g1as, g1ad, hB, as_v, ad_v, m_enc, sl);
    k_gat_max<<<(NE + 255) / 256, 256, 0, stream>>>(src, dst, as_v, ad_v, m_enc);
    k_gat_self<<<(NN * 64 + 255) / 256, 256, 0, stream>>>(m_enc, sl, hB, m_f, denom, hC);
    k_gat_expsum<<<(NE + 255) / 256, 256, 0, stream>>>(src, dst, as_v, ad_v, m_f, ew, denom);
    k_gat_scatter<<<(int)(((long long)NE * 64 + 255) / 256), 256, 0, stream>>>(src, dst, ew, hB, hC);
    k_gat_final<<<(NN * 64 + 255) / 256, 256, 0, stream>>>(hC, denom, g1b, hC);

    // GAT layer 2: hC [N,64] -> hD [N,64]
    k_gat_h<64><<<(NN + 255) / 256, 256, 0, stream>>>(hC, g2w, g2as, g2ad, hB, as_v, ad_v, m_enc, sl);
    k_gat_max<<<(NE + 255) / 256, 256, 0, stream>>>(src, dst, as_v, ad_v, m_enc);
    k_gat_self<<<(NN * 64 + 255) / 256, 256, 0, stream>>>(m_enc, sl, hB, m_f, denom, hD);
    k_gat_expsum<<<(NE + 255) / 256, 256, 0, stream>>>(src, dst, as_v, ad_v, m_f, ew, denom);
    k_gat_scatter<<<(int)(((long long)NE * 64 + 255) / 256), 256, 0, stream>>>(src, dst, ew, hB, hD);
    k_gat_final<<<(NN * 64 + 255) / 256, 256, 0, stream>>>(hD, denom, g2b, hD);

    // global mean pool
    k_pool1<<<(NN + 511) / 512, 256, 0, stream>>>(hD, batch, gsum, gcnt);
    k_pool2<<<(NG * 64 + 255) / 256, 256, 0, stream>>>(gsum, gcnt, out);
}

// Round 2
// 933.759 us; speedup vs baseline: 1.5932x; 1.5932x over previous
//
#include <hip/hip_runtime.h>

#define NN 50000
#define NE 400000
#define NG 32
#define SLOPE 0.2f

typedef __attribute__((ext_vector_type(4))) float f32x4;
typedef __attribute__((ext_vector_type(8))) short s16x8;

__device__ __forceinline__ float lrelu(float v) { return v > 0.f ? v : SLOPE * v; }
__device__ __forceinline__ unsigned short f2bf(float f) {
    union { float f; unsigned u; } c; c.f = f;
    unsigned r = c.u + 0x7fffu + ((c.u >> 16) & 1u);
    return (unsigned short)(r >> 16);
}
__device__ __forceinline__ float bf2f(unsigned short b) {
    union { unsigned u; float f; } c; c.u = ((unsigned)b) << 16; return c.f;
}

// ---------------- CSR build ----------------
__global__ __launch_bounds__(256) void k_hist(const int* __restrict__ dst, int* __restrict__ deg) {
    int e = blockIdx.x * 256 + threadIdx.x;
    if (e < NE) atomicAdd(&deg[dst[e]], 1);
}

#define SCAN_C 49
__global__ __launch_bounds__(1024) void k_scan(const int* __restrict__ deg,
                                               int* __restrict__ rowptr, int* __restrict__ cursor) {
    __shared__ int ps[1024];
    const int t = threadIdx.x;
    const int base = t * SCAN_C;
    int s = 0;
    for (int j = 0; j < SCAN_C; ++j) { int idx = base + j; if (idx < NN) s += deg[idx]; }
    ps[t] = s;
    __syncthreads();
    for (int off = 1; off < 1024; off <<= 1) {
        int v = (t >= off) ? ps[t - off] : 0;
        __syncthreads();
        ps[t] += v;
        __syncthreads();
    }
    int run = (t == 0) ? 0 : ps[t - 1];
    for (int j = 0; j < SCAN_C; ++j) {
        int idx = base + j;
        if (idx < NN) { rowptr[idx] = run; cursor[idx] = run; run += deg[idx]; }
    }
    if (t == 1023) rowptr[NN] = NE;
}

__global__ __launch_bounds__(256) void k_perm(const int* __restrict__ dst,
                                              int* __restrict__ cursor, int* __restrict__ eid) {
    int e = blockIdx.x * 256 + threadIdx.x;
    if (e < NE) { int p = atomicAdd(&cursor[dst[e]], 1); eid[p] = e; }
}

// ---------------- EdgeMLP: 3->128->64, h2 in bf16 ----------------
__global__ __launch_bounds__(128) void k_mlp(
    const float* __restrict__ ea,
    const float* __restrict__ w1, const float* __restrict__ b1,
    const float* __restrict__ w2, const float* __restrict__ b2,
    unsigned short* __restrict__ h2)
{
    const int e = blockIdx.x * 128 + threadIdx.x;  // 3125*128 == NE exactly
    const float ea0 = ea[e * 3 + 0], ea1 = ea[e * 3 + 1], ea2 = ea[e * 3 + 2];
    float acc[64];
#pragma unroll
    for (int o = 0; o < 64; ++o) acc[o] = b2[o];
#pragma unroll 2
    for (int j = 0; j < 128; ++j) {
        float hj = fmaf(ea0, w1[j], fmaf(ea1, w1[128 + j], fmaf(ea2, w1[256 + j], b1[j])));
        hj = fmaxf(hj, 0.f);
        const float* __restrict__ w2r = w2 + j * 64;
#pragma unroll
        for (int o = 0; o < 64; ++o) acc[o] = fmaf(hj, w2r[o], acc[o]);
    }
    unsigned pk[32];
#pragma unroll
    for (int q = 0; q < 32; ++q) {
        pk[q] = (unsigned)f2bf(fmaxf(acc[2 * q], 0.f)) |
                ((unsigned)f2bf(fmaxf(acc[2 * q + 1], 0.f)) << 16);
    }
    uint4* out = (uint4*)(h2 + (size_t)e * 64);
#pragma unroll
    for (int q = 0; q < 8; ++q)
        out[q] = make_uint4(pk[4 * q], pk[4 * q + 1], pk[4 * q + 2], pk[4 * q + 3]);
}

// ---------------- msg GEMM: [400k,64] @ [64,512] bf16 MFMA, fused x-contraction ----------------
// Block: 512 threads (8 waves as 2M x 4N), BM=64 edges, N=512, K=64.
// w3 staged transposed+bf16 in LDS with 16B XOR swizzle; per-lane epilogue combines the
// 4 same-o fragments in registers, LDS-reduces across N-waves, writes msg bf16.
__global__ __launch_bounds__(512) void k_msg(
    const unsigned short* __restrict__ h2, const float* __restrict__ w3,
    const float* __restrict__ b3, const float* __restrict__ x,
    const int* __restrict__ src, unsigned short* __restrict__ msg)
{
    __shared__ unsigned short w3t[512 * 64];  // [n][k] bf16, swizzled, 64 KB
    __shared__ float x_s[64 * 16];
    __shared__ float msg_s[64 * 32];
    __shared__ int s_idx[64];
    const int t = threadIdx.x;
    const int e0 = blockIdx.x * 64;  // 6250*64 == NE exactly

    // stage w3 -> LDS (read coalesced over n, scatter-write transposed bf16)
    for (int v = t; v < 64 * 512; v += 512) {
        int k = v >> 9, n = v & 511;
        int byte = (n << 7) | ((k << 1) ^ ((n & 7) << 4));
        *(unsigned short*)((char*)w3t + byte) = f2bf(w3[v]);
    }
    if (t < 64) s_idx[t] = src[e0 + t];
    __syncthreads();
    for (int v = t; v < 64 * 16; v += 512)
        x_s[v] = x[(size_t)s_idx[v >> 4] * 16 + (v & 15)];
    __syncthreads();
    // init msg_s with the b3 bias term: Sum_i x[i]*b3[i*32+o]
    for (int v = t; v < 64 * 32; v += 512) {
        int r = v >> 5, o = v & 31;
        float s = 0.f;
#pragma unroll
        for (int i = 0; i < 16; ++i) s = fmaf(x_s[r * 16 + i], b3[i * 32 + o], s);
        msg_s[v] = s;
    }
    __syncthreads();

    const int wid = t >> 6, lane = t & 63;
    const int wm = wid >> 2, wn = wid & 3;
    const int lr = lane & 15, lg = lane >> 4;

    f32x4 acc[2][8];
#pragma unroll
    for (int fm = 0; fm < 2; ++fm)
#pragma unroll
        for (int fn = 0; fn < 8; ++fn) acc[fm][fn] = (f32x4){0.f, 0.f, 0.f, 0.f};

#pragma unroll
    for (int kc = 0; kc < 2; ++kc) {
        s16x8 a[2];
#pragma unroll
        for (int fm = 0; fm < 2; ++fm) {
            const unsigned short* ap =
                h2 + (size_t)(e0 + wm * 32 + fm * 16 + lr) * 64 + kc * 32 + lg * 8;
            a[fm] = *(const s16x8*)ap;
        }
#pragma unroll
        for (int fn = 0; fn < 8; ++fn) {
            const int n = wn * 128 + fn * 16 + lr;
            const int kbyte = ((kc * 32 + lg * 8) << 1) ^ ((n & 7) << 4);
            s16x8 b = *(const s16x8*)((const char*)w3t + (n << 7) + kbyte);
#pragma unroll
            for (int fm = 0; fm < 2; ++fm)
                acc[fm][fn] = __builtin_amdgcn_mfma_f32_16x16x32_bf16(a[fm], b, acc[fm][fn], 0, 0, 0);
        }
    }

    // epilogue: msg[r][o] += Sum_i x_s[r][i] * g[r][i*32+o]
    // lane's cols: n = wn*128 + fn*16 + lr -> o = (fn even ? lr : 16+lr), i = wn*4 + fn/2
#pragma unroll
    for (int fm = 0; fm < 2; ++fm) {
#pragma unroll
        for (int q = 0; q < 4; ++q) {
            const int r = wm * 32 + fm * 16 + lg * 4 + q;  // D row = (lane>>4)*4 + reg
            float p0 = 0.f, p1 = 0.f;
#pragma unroll
            for (int h = 0; h < 4; ++h) {
                const float xv = x_s[r * 16 + wn * 4 + h];
                p0 = fmaf(acc[fm][2 * h][q], xv, p0);
                p1 = fmaf(acc[fm][2 * h + 1][q], xv, p1);
            }
            atomicAdd(&msg_s[r * 32 + lr], p0);
            atomicAdd(&msg_s[r * 32 + 16 + lr], p1);
        }
    }
    __syncthreads();
    for (int v = t; v < 64 * 16; v += 512) {
        int r = v >> 4, o2 = (v & 15) * 2;
        unsigned u = (unsigned)f2bf(msg_s[r * 32 + o2]) |
                     ((unsigned)f2bf(msg_s[r * 32 + o2 + 1]) << 16);
        *(unsigned*)(msg + (size_t)(e0 + r) * 32 + o2) = u;
    }
}

// ---------------- aggregate msg by dst (CSR gather) + root transform ----------------
__global__ __launch_bounds__(256) void k_agg(
    const unsigned short* __restrict__ msg, const int* __restrict__ rowptr,
    const int* __restrict__ eid, const float* __restrict__ x,
    const float* __restrict__ rw, const float* __restrict__ cb, float* __restrict__ h1)
{
    const int n = (blockIdx.x * 256 + threadIdx.x) >> 6;
    if (n >= NN) return;
    const int lane = threadIdx.x & 63;
    if (lane >= 32) return;
    const int o = lane;
    const int r0 = rowptr[n], r1 = rowptr[n + 1];
    float acc = 0.f;
    for (int j = r0; j < r1; ++j)
        acc += bf2f(msg[(size_t)eid[j] * 32 + o]);
    const float* __restrict__ xr = x + (size_t)n * 16;
    float root = cb[o];
#pragma unroll
    for (int i = 0; i < 16; ++i) root = fmaf(xr[i], rw[i * 32 + o], root);
    h1[(size_t)n * 32 + o] = fmaxf(acc + root, 0.f);
}

// ---------------- GAT: node transform + attention coefficients ----------------
template <int FI>
__global__ __launch_bounds__(256) void k_gat_h(
    const float* __restrict__ hin, const float* __restrict__ W,
    const float* __restrict__ av_s, const float* __restrict__ av_d,
    float* __restrict__ h, float* __restrict__ as_v, float* __restrict__ ad_v)
{
    const int n = blockIdx.x * 256 + threadIdx.x;
    if (n >= NN) return;
    float acc[64];
#pragma unroll
    for (int o = 0; o < 64; ++o) acc[o] = 0.f;
#pragma unroll 2
    for (int i = 0; i < FI; ++i) {
        const float xi = hin[(size_t)n * FI + i];
        const float* __restrict__ wr = W + i * 64;
#pragma unroll
        for (int o = 0; o < 64; ++o) acc[o] = fmaf(xi, wr[o], acc[o]);
    }
    float s = 0.f, d = 0.f;
#pragma unroll
    for (int o = 0; o < 64; ++o) {
        h[(size_t)n * 64 + o] = acc[o];
        s = fmaf(acc[o], av_s[o], s);
        d = fmaf(acc[o], av_d[o], d);
    }
    as_v[n] = s;
    ad_v[n] = d;
}

// ---------------- GAT: per-node softmax + weighted gather (one wave per node) ----------------
__global__ __launch_bounds__(256) void k_gat_node(
    const int* __restrict__ rowptr, const int* __restrict__ eid, const int* __restrict__ src,
    const float* __restrict__ h, const float* __restrict__ as_v, const float* __restrict__ ad_v,
    const float* __restrict__ b, float* __restrict__ out)
{
    const int n = (blockIdx.x * 256 + threadIdx.x) >> 6;
    if (n >= NN) return;
    const int lane = threadIdx.x & 63;
    const int r0 = rowptr[n], r1 = rowptr[n + 1];
    const float adn = ad_v[n];
    const float l_self = lrelu(as_v[n] + adn);
    // pass 1: max (lane-parallel over edges)
    float m = l_self;
    for (int j = r0 + lane; j < r1; j += 64)
        m = fmaxf(m, lrelu(as_v[src[eid[j]]] + adn));
#pragma unroll
    for (int off = 32; off; off >>= 1) m = fmaxf(m, __shfl_xor(m, off));
    // pass 2: denom (lane-parallel, loads now hot)
    float s = 0.f;
    for (int j = r0 + lane; j < r1; j += 64)
        s += expf(lrelu(as_v[src[eid[j]]] + adn) - m);
#pragma unroll
    for (int off = 32; off; off >>= 1) s += __shfl_xor(s, off);
    const float w_self = expf(l_self - m);
    s += w_self;
    // pass 3: features (sequential edges, lanes = 64 features)
    float acc = w_self * h[(size_t)n * 64 + lane];
    for (int j = r0; j < r1; ++j) {
        const int sn = src[eid[j]];
        const float w = expf(lrelu(as_v[sn] + adn) - m);
        acc = fmaf(w, h[(size_t)sn * 64 + lane], acc);
    }
    out[(size_t)n * 64 + lane] = fmaxf(acc / s + b[lane], 0.f);
}

// ---------------- global mean pool ----------------
__global__ __launch_bounds__(256) void k_pool1(
    const float* __restrict__ h, const int* __restrict__ batch,
    float* __restrict__ gsum, float* __restrict__ gcnt)
{
    __shared__ float ls[NG * 64];
    __shared__ float lc[NG];
    for (int j = threadIdx.x; j < NG * 64; j += 256) ls[j] = 0.f;
    if (threadIdx.x < NG) lc[threadIdx.x] = 0.f;
    __syncthreads();
    const int base = blockIdx.x * 512;
    for (int idx = threadIdx.x; idx < 512 * 64; idx += 256) {
        const int nl = idx >> 6, f = idx & 63;
        const int n = base + nl;
        if (n < NN) {
            const int g = batch[n];
            atomicAdd(&ls[g * 64 + f], h[(size_t)n * 64 + f]);
            if (f == 0) atomicAdd(&lc[g], 1.f);
        }
    }
    __syncthreads();
    for (int j = threadIdx.x; j < NG * 64; j += 256) atomicAdd(&gsum[j], ls[j]);
    if (threadIdx.x < NG) atomicAdd(&gcnt[threadIdx.x], lc[threadIdx.x]);
}

__global__ __launch_bounds__(256) void k_pool2(
    const float* __restrict__ gsum, const float* __restrict__ gcnt, float* __restrict__ out)
{
    const int idx = blockIdx.x * 256 + threadIdx.x;
    if (idx >= NG * 64) return;
    out[idx] = gsum[idx] / fmaxf(gcnt[idx >> 6], 1.f);
}

extern "C" void kernel_launch(void* const* d_in, const int* in_sizes, int n_in,
                              void* d_out, int out_size, void* d_ws, size_t ws_size,
                              hipStream_t stream)
{
    const float* x     = (const float*)d_in[0];
    const float* ea    = (const float*)d_in[1];
    const int*   ei    = (const int*)d_in[2];
    const int*   batch = (const int*)d_in[3];
    const float* w1 = (const float*)d_in[4];   const float* b1 = (const float*)d_in[5];
    const float* w2 = (const float*)d_in[6];   const float* b2 = (const float*)d_in[7];
    const float* w3 = (const float*)d_in[8];   const float* b3 = (const float*)d_in[9];
    const float* rw = (const float*)d_in[10];  const float* cb = (const float*)d_in[11];
    const float* g1w  = (const float*)d_in[12]; const float* g1as = (const float*)d_in[13];
    const float* g1ad = (const float*)d_in[14]; const float* g1b  = (const float*)d_in[15];
    const float* g2w  = (const float*)d_in[16]; const float* g2as = (const float*)d_in[17];
    const float* g2ad = (const float*)d_in[18]; const float* g2b  = (const float*)d_in[19];
    const int* src = ei;
    const int* dst = ei + NE;
    float* out = (float*)d_out;
    (void)in_sizes; (void)n_in; (void)out_size; (void)ws_size;

    char* ws = (char*)d_ws;
    size_t off = 0;
    auto alloc = [&](size_t bytes) -> char* {
        char* p = ws + off;
        off += (bytes + 255) & ~(size_t)255;
        return p;
    };
    int*  deg    = (int*)alloc((size_t)NN * 4);
    int*  cursor = (int*)alloc((size_t)NN * 4);
    int*  rowptr = (int*)alloc((size_t)(NN + 1) * 4);
    int*  eid    = (int*)alloc((size_t)NE * 4);
    unsigned short* h2  = (unsigned short*)alloc((size_t)NE * 64 * 2);  // 51.2 MB, reused below
    unsigned short* msg = (unsigned short*)alloc((size_t)NE * 32 * 2);  // 25.6 MB
    float* h1   = (float*)alloc((size_t)NN * 32 * 4);
    float* as_v = (float*)alloc((size_t)NN * 4);
    float* ad_v = (float*)alloc((size_t)NN * 4);
    float* gsum = (float*)alloc((size_t)NG * 64 * 4);
    float* gcnt = (float*)alloc((size_t)NG * 4);
    // h2 region is dead after k_msg; reuse it for the GAT feature buffers (38.4 MB <= 51.2 MB)
    float* hB = (float*)h2;                          // transformed h [N,64]
    float* hC = (float*)((char*)h2 + (size_t)NN * 64 * 4);
    float* hD = (float*)((char*)h2 + (size_t)NN * 64 * 8);

    hipMemsetAsync(deg, 0, (size_t)NN * 4, stream);
    hipMemsetAsync(gsum, 0, (size_t)NG * 64 * 4, stream);
    hipMemsetAsync(gcnt, 0, (size_t)NG * 4, stream);

    // CSR build
    k_hist<<<(NE + 255) / 256, 256, 0, stream>>>(dst, deg);
    k_scan<<<1, 1024, 0, stream>>>(deg, rowptr, cursor);
    k_perm<<<(NE + 255) / 256, 256, 0, stream>>>(dst, cursor, eid);

    // NNConv
    k_mlp<<<NE / 128, 128, 0, stream>>>(ea, w1, b1, w2, b2, h2);
    k_msg<<<NE / 64, 512, 0, stream>>>(h2, w3, b3, x, src, msg);
    k_agg<<<(NN * 64 + 255) / 256, 256, 0, stream>>>(msg, rowptr, eid, x, rw, cb, h1);

    // GAT layer 1
    k_gat_h<32><<<(NN + 255) / 256, 256, 0, stream>>>(h1, g1w, g1as, g1ad, hB, as_v, ad_v);
    k_gat_node<<<(NN * 64 + 255) / 256, 256, 0, stream>>>(rowptr, eid, src, hB, as_v, ad_v, g1b, hC);

    // GAT layer 2
    k_gat_h<64><<<(NN + 255) / 256, 256, 0, stream>>>(hC, g2w, g2as, g2ad, hB, as_v, ad_v);
    k_gat_node<<<(NN * 64 + 255) / 256, 256, 0, stream>>>(rowptr, eid, src, hB, as_v, ad_v, g2b, hD);

    // pool
    k_pool1<<<(NN + 511) / 512, 256, 0, stream>>>(hD, batch, gsum, gcnt);
    k_pool2<<<(NG * 64 + 255) / 256, 256, 0, stream>>>(gsum, gcnt, out);
}

// Round 3
// 885.532 us; speedup vs baseline: 1.6799x; 1.0545x over previous
//
#include <hip/hip_runtime.h>

#define NN 50000
#define NE 400000
#define NG 32
#define SLOPE 0.2f

typedef __attribute__((ext_vector_type(4))) float f32x4;
typedef __attribute__((ext_vector_type(8))) short s16x8;

__device__ __forceinline__ float lrelu(float v) { return v > 0.f ? v : SLOPE * v; }
__device__ __forceinline__ unsigned short f2bf(float f) {
    union { float f; unsigned u; } c; c.f = f;
    unsigned r = c.u + 0x7fffu + ((c.u >> 16) & 1u);
    return (unsigned short)(r >> 16);
}
__device__ __forceinline__ float bf2f(unsigned short b) {
    union { unsigned u; float f; } c; c.u = ((unsigned)b) << 16; return c.f;
}

// ---------------- CSR build ----------------
__global__ __launch_bounds__(256) void k_hist(const int* __restrict__ dst, int* __restrict__ deg) {
    int e = blockIdx.x * 256 + threadIdx.x;
    if (e < NE) atomicAdd(&deg[dst[e]], 1);
}

#define SCAN_C 49
__global__ __launch_bounds__(1024) void k_scan(const int* __restrict__ deg,
                                               int* __restrict__ rowptr, int* __restrict__ cursor) {
    __shared__ int ps[1024];
    const int t = threadIdx.x;
    const int base = t * SCAN_C;
    int s = 0;
    for (int j = 0; j < SCAN_C; ++j) { int idx = base + j; if (idx < NN) s += deg[idx]; }
    ps[t] = s;
    __syncthreads();
    for (int off = 1; off < 1024; off <<= 1) {
        int v = (t >= off) ? ps[t - off] : 0;
        __syncthreads();
        ps[t] += v;
        __syncthreads();
    }
    int run = (t == 0) ? 0 : ps[t - 1];
    for (int j = 0; j < SCAN_C; ++j) {
        int idx = base + j;
        if (idx < NN) { rowptr[idx] = run; cursor[idx] = run; run += deg[idx]; }
    }
    if (t == 1023) rowptr[NN] = NE;
}

__global__ __launch_bounds__(256) void k_perm(const int* __restrict__ dst,
                                              int* __restrict__ cursor, int* __restrict__ eid) {
    int e = blockIdx.x * 256 + threadIdx.x;
    if (e < NE) { int p = atomicAdd(&cursor[dst[e]], 1); eid[p] = e; }
}

// ---------------- one-time: w3 -> bf16, transposed [n][k], XOR-swizzled ----------------
__global__ __launch_bounds__(256) void k_w3prep(const float* __restrict__ w3,
                                                unsigned short* __restrict__ w3t_g) {
    const int v = blockIdx.x * 256 + threadIdx.x;  // v = k*512 + n
    if (v >= 64 * 512) return;
    const int k = v >> 9, n = v & 511;
    const int byte = (n << 7) | ((k << 1) ^ ((n & 7) << 4));
    *(unsigned short*)((char*)w3t_g + byte) = f2bf(w3[v]);
}

// ---------------- EdgeMLP: 3->128->64, h2 in bf16 ----------------
__global__ __launch_bounds__(128) void k_mlp(
    const float* __restrict__ ea,
    const float* __restrict__ w1, const float* __restrict__ b1,
    const float* __restrict__ w2, const float* __restrict__ b2,
    unsigned short* __restrict__ h2)
{
    const int e = blockIdx.x * 128 + threadIdx.x;  // 3125*128 == NE exactly
    const float ea0 = ea[e * 3 + 0], ea1 = ea[e * 3 + 1], ea2 = ea[e * 3 + 2];
    float acc[64];
#pragma unroll
    for (int o = 0; o < 64; ++o) acc[o] = b2[o];
#pragma unroll 2
    for (int j = 0; j < 128; ++j) {
        float hj = fmaf(ea0, w1[j], fmaf(ea1, w1[128 + j], fmaf(ea2, w1[256 + j], b1[j])));
        hj = fmaxf(hj, 0.f);
        const float* __restrict__ w2r = w2 + j * 64;
#pragma unroll
        for (int o = 0; o < 64; ++o) acc[o] = fmaf(hj, w2r[o], acc[o]);
    }
    unsigned pk[32];
#pragma unroll
    for (int q = 0; q < 32; ++q) {
        pk[q] = (unsigned)f2bf(fmaxf(acc[2 * q], 0.f)) |
                ((unsigned)f2bf(fmaxf(acc[2 * q + 1], 0.f)) << 16);
    }
    uint4* out = (uint4*)(h2 + (size_t)e * 64);
#pragma unroll
    for (int q = 0; q < 8; ++q)
        out[q] = make_uint4(pk[4 * q], pk[4 * q + 1], pk[4 * q + 2], pk[4 * q + 3]);
}

// ---------------- msg GEMM: persistent blocks, w3t staged once, grid-stride tiles ----------------
#define NTILE (NE / 64)
#define MSG_GRID 512
__global__ __launch_bounds__(512) void k_msg(
    const unsigned short* __restrict__ h2, const unsigned short* __restrict__ w3t_g,
    const float* __restrict__ b3, const float* __restrict__ x,
    const int* __restrict__ src, unsigned short* __restrict__ msg)
{
    __shared__ unsigned short w3t[512 * 64];  // 64 KB, pre-swizzled
    __shared__ float x_s[64 * 16];
    __shared__ float msg_s[64 * 32];
    __shared__ int s_idx[64];
    const int t = threadIdx.x;

    // stage w3t once: linear 16B copy preserves the pre-applied swizzle
    {
        const uint4* g = (const uint4*)w3t_g;
        uint4* l = (uint4*)w3t;
        for (int v = t; v < 4096; v += 512) l[v] = g[v];
    }

    const int wid = t >> 6, lane = t & 63;
    const int wm = wid >> 2, wn = wid & 3;
    const int lr = lane & 15, lg = lane >> 4;

    // per-lane b3 column values (accumulator seed), loop-invariant
    float b3r[8];
#pragma unroll
    for (int fn = 0; fn < 8; ++fn) b3r[fn] = b3[wn * 128 + fn * 16 + lr];

    __syncthreads();

    for (int tile = blockIdx.x; tile < NTILE; tile += MSG_GRID) {
        const int e0 = tile * 64;
        if (t < 64) s_idx[t] = src[e0 + t];
        for (int v = t; v < 64 * 32; v += 512) msg_s[v] = 0.f;
        __syncthreads();
        for (int v = t; v < 64 * 16; v += 512)
            x_s[v] = x[(size_t)s_idx[v >> 4] * 16 + (v & 15)];
        __syncthreads();

        f32x4 acc[2][8];
#pragma unroll
        for (int fm = 0; fm < 2; ++fm)
#pragma unroll
            for (int fn = 0; fn < 8; ++fn)
                acc[fm][fn] = (f32x4){b3r[fn], b3r[fn], b3r[fn], b3r[fn]};

#pragma unroll
        for (int kc = 0; kc < 2; ++kc) {
            s16x8 a[2];
#pragma unroll
            for (int fm = 0; fm < 2; ++fm) {
                const unsigned short* ap =
                    h2 + (size_t)(e0 + wm * 32 + fm * 16 + lr) * 64 + kc * 32 + lg * 8;
                a[fm] = *(const s16x8*)ap;
            }
#pragma unroll
            for (int fn = 0; fn < 8; ++fn) {
                const int n = wn * 128 + fn * 16 + lr;
                const int kbyte = ((kc * 32 + lg * 8) << 1) ^ ((n & 7) << 4);
                s16x8 b = *(const s16x8*)((const char*)w3t + (n << 7) + kbyte);
#pragma unroll
                for (int fm = 0; fm < 2; ++fm)
                    acc[fm][fn] = __builtin_amdgcn_mfma_f32_16x16x32_bf16(a[fm], b, acc[fm][fn], 0, 0, 0);
            }
        }

        // epilogue: contract i with x_s; lane's col n -> o=(n&31), i=(n>>5)=wn*4+fn/2
#pragma unroll
        for (int fm = 0; fm < 2; ++fm) {
#pragma unroll
            for (int q = 0; q < 4; ++q) {
                const int r = wm * 32 + fm * 16 + lg * 4 + q;
                float p0 = 0.f, p1 = 0.f;
#pragma unroll
                for (int h = 0; h < 4; ++h) {
                    const float xv = x_s[r * 16 + wn * 4 + h];
                    p0 = fmaf(acc[fm][2 * h][q], xv, p0);
                    p1 = fmaf(acc[fm][2 * h + 1][q], xv, p1);
                }
                atomicAdd(&msg_s[r * 32 + lr], p0);
                atomicAdd(&msg_s[r * 32 + 16 + lr], p1);
            }
        }
        __syncthreads();
        for (int v = t; v < 64 * 16; v += 512) {
            int r = v >> 4, o2 = (v & 15) * 2;
            unsigned u = (unsigned)f2bf(msg_s[r * 32 + o2]) |
                         ((unsigned)f2bf(msg_s[r * 32 + o2 + 1]) << 16);
            *(unsigned*)(msg + (size_t)(e0 + r) * 32 + o2) = u;
        }
        __syncthreads();  // protect msg_s/x_s reuse next iteration
    }
}

// ---------------- aggregate msg by dst (CSR gather) + root transform ----------------
__global__ __launch_bounds__(256) void k_agg(
    const unsigned short* __restrict__ msg, const int* __restrict__ rowptr,
    const int* __restrict__ eid, const float* __restrict__ x,
    const float* __restrict__ rw, const float* __restrict__ cb, float* __restrict__ h1)
{
    const int n = (blockIdx.x * 256 + threadIdx.x) >> 6;
    if (n >= NN) return;
    const int lane = threadIdx.x & 63;
    if (lane >= 32) return;
    const int o = lane;
    const int r0 = rowptr[n], r1 = rowptr[n + 1];
    float acc = 0.f;
    for (int j = r0; j < r1; ++j)
        acc += bf2f(msg[(size_t)eid[j] * 32 + o]);
    const float* __restrict__ xr = x + (size_t)n * 16;
    float root = cb[o];
#pragma unroll
    for (int i = 0; i < 16; ++i) root = fmaf(xr[i], rw[i * 32 + o], root);
    h1[(size_t)n * 32 + o] = fmaxf(acc + root, 0.f);
}

// ---------------- GAT: node transform + attention coefficients ----------------
template <int FI>
__global__ __launch_bounds__(256) void k_gat_h(
    const float* __restrict__ hin, const float* __restrict__ W,
    const float* __restrict__ av_s, const float* __restrict__ av_d,
    float* __restrict__ h, float* __restrict__ as_v, float* __restrict__ ad_v)
{
    const int n = blockIdx.x * 256 + threadIdx.x;
    if (n >= NN) return;
    float acc[64];
#pragma unroll
    for (int o = 0; o < 64; ++o) acc[o] = 0.f;
#pragma unroll 2
    for (int i = 0; i < FI; ++i) {
        const float xi = hin[(size_t)n * FI + i];
        const float* __restrict__ wr = W + i * 64;
#pragma unroll
        for (int o = 0; o < 64; ++o) acc[o] = fmaf(xi, wr[o], acc[o]);
    }
    float s = 0.f, d = 0.f;
#pragma unroll
    for (int o = 0; o < 64; ++o) {
        h[(size_t)n * 64 + o] = acc[o];
        s = fmaf(acc[o], av_s[o], s);
        d = fmaf(acc[o], av_d[o], d);
    }
    as_v[n] = s;
    ad_v[n] = d;
}

// ---------------- GAT: per-node softmax + weighted gather (one wave per node) ----------------
__global__ __launch_bounds__(256) void k_gat_node(
    const int* __restrict__ rowptr, const int* __restrict__ eid, const int* __restrict__ src,
    const float* __restrict__ h, const float* __restrict__ as_v, const float* __restrict__ ad_v,
    const float* __restrict__ b, float* __restrict__ out)
{
    const int n = (blockIdx.x * 256 + threadIdx.x) >> 6;
    if (n >= NN) return;
    const int lane = threadIdx.x & 63;
    const int r0 = rowptr[n], r1 = rowptr[n + 1];
    const float adn = ad_v[n];
    const float l_self = lrelu(as_v[n] + adn);
    float m = l_self;
    for (int j = r0 + lane; j < r1; j += 64)
        m = fmaxf(m, lrelu(as_v[src[eid[j]]] + adn));
#pragma unroll
    for (int off = 32; off; off >>= 1) m = fmaxf(m, __shfl_xor(m, off));
    float s = 0.f;
    for (int j = r0 + lane; j < r1; j += 64)
        s += expf(lrelu(as_v[src[eid[j]]] + adn) - m);
#pragma unroll
    for (int off = 32; off; off >>= 1) s += __shfl_xor(s, off);
    const float w_self = expf(l_self - m);
    s += w_self;
    float acc = w_self * h[(size_t)n * 64 + lane];
    for (int j = r0; j < r1; ++j) {
        const int sn = src[eid[j]];
        const float w = expf(lrelu(as_v[sn] + adn) - m);
        acc = fmaf(w, h[(size_t)sn * 64 + lane], acc);
    }
    out[(size_t)n * 64 + lane] = fmaxf(acc / s + b[lane], 0.f);
}

// ---------------- global mean pool ----------------
__global__ __launch_bounds__(256) void k_pool1(
    const float* __restrict__ h, const int* __restrict__ batch,
    float* __restrict__ gsum, float* __restrict__ gcnt)
{
    __shared__ float ls[NG * 64];
    __shared__ float lc[NG];
    for (int j = threadIdx.x; j < NG * 64; j += 256) ls[j] = 0.f;
    if (threadIdx.x < NG) lc[threadIdx.x] = 0.f;
    __syncthreads();
    const int base = blockIdx.x * 512;
    for (int idx = threadIdx.x; idx < 512 * 64; idx += 256) {
        const int nl = idx >> 6, f = idx & 63;
        const int n = base + nl;
        if (n < NN) {
            const int g = batch[n];
            atomicAdd(&ls[g * 64 + f], h[(size_t)n * 64 + f]);
            if (f == 0) atomicAdd(&lc[g], 1.f);
        }
    }
    __syncthreads();
    for (int j = threadIdx.x; j < NG * 64; j += 256) atomicAdd(&gsum[j], ls[j]);
    if (threadIdx.x < NG) atomicAdd(&gcnt[threadIdx.x], lc[threadIdx.x]);
}

__global__ __launch_bounds__(256) void k_pool2(
    const float* __restrict__ gsum, const float* __restrict__ gcnt, float* __restrict__ out)
{
    const int idx = blockIdx.x * 256 + threadIdx.x;
    if (idx >= NG * 64) return;
    out[idx] = gsum[idx] / fmaxf(gcnt[idx >> 6], 1.f);
}

extern "C" void kernel_launch(void* const* d_in, const int* in_sizes, int n_in,
                              void* d_out, int out_size, void* d_ws, size_t ws_size,
                              hipStream_t stream)
{
    const float* x     = (const float*)d_in[0];
    const float* ea    = (const float*)d_in[1];
    const int*   ei    = (const int*)d_in[2];
    const int*   batch = (const int*)d_in[3];
    const float* w1 = (const float*)d_in[4];   const float* b1 = (const float*)d_in[5];
    const float* w2 = (const float*)d_in[6];   const float* b2 = (const float*)d_in[7];
    const float* w3 = (const float*)d_in[8];   const float* b3 = (const float*)d_in[9];
    const float* rw = (const float*)d_in[10];  const float* cb = (const float*)d_in[11];
    const float* g1w  = (const float*)d_in[12]; const float* g1as = (const float*)d_in[13];
    const float* g1ad = (const float*)d_in[14]; const float* g1b  = (const float*)d_in[15];
    const float* g2w  = (const float*)d_in[16]; const float* g2as = (const float*)d_in[17];
    const float* g2ad = (const float*)d_in[18]; const float* g2b  = (const float*)d_in[19];
    const int* src = ei;
    const int* dst = ei + NE;
    float* out = (float*)d_out;
    (void)in_sizes; (void)n_in; (void)out_size; (void)ws_size;

    char* ws = (char*)d_ws;
    size_t off = 0;
    auto alloc = [&](size_t bytes) -> char* {
        char* p = ws + off;
        off += (bytes + 255) & ~(size_t)255;
        return p;
    };
    int*  deg    = (int*)alloc((size_t)NN * 4);
    int*  cursor = (int*)alloc((size_t)NN * 4);
    int*  rowptr = (int*)alloc((size_t)(NN + 1) * 4);
    int*  eid    = (int*)alloc((size_t)NE * 4);
    unsigned short* w3t_g = (unsigned short*)alloc((size_t)64 * 512 * 2);
    unsigned short* h2  = (unsigned short*)alloc((size_t)NE * 64 * 2);  // 51.2 MB, reused below
    unsigned short* msg = (unsigned short*)alloc((size_t)NE * 32 * 2);  // 25.6 MB
    float* h1   = (float*)alloc((size_t)NN * 32 * 4);
    float* as_v = (float*)alloc((size_t)NN * 4);
    float* ad_v = (float*)alloc((size_t)NN * 4);
    float* gsum = (float*)alloc((size_t)NG * 64 * 4);
    float* gcnt = (float*)alloc((size_t)NG * 4);
    // h2 region is dead after k_msg; reuse for GAT feature buffers (38.4 MB <= 51.2 MB)
    float* hB = (float*)h2;
    float* hC = (float*)((char*)h2 + (size_t)NN * 64 * 4);
    float* hD = (float*)((char*)h2 + (size_t)NN * 64 * 8);

    hipMemsetAsync(deg, 0, (size_t)NN * 4, stream);
    hipMemsetAsync(gsum, 0, (size_t)NG * 64 * 4, stream);
    hipMemsetAsync(gcnt, 0, (size_t)NG * 4, stream);

    // CSR build
    k_hist<<<(NE + 255) / 256, 256, 0, stream>>>(dst, deg);
    k_scan<<<1, 1024, 0, stream>>>(deg, rowptr, cursor);
    k_perm<<<(NE + 255) / 256, 256, 0, stream>>>(dst, cursor, eid);

    // NNConv
    k_w3prep<<<(64 * 512 + 255) / 256, 256, 0, stream>>>(w3, w3t_g);
    k_mlp<<<NE / 128, 128, 0, stream>>>(ea, w1, b1, w2, b2, h2);
    k_msg<<<MSG_GRID, 512, 0, stream>>>(h2, w3t_g, b3, x, src, msg);
    k_agg<<<(NN * 64 + 255) / 256, 256, 0, stream>>>(msg, rowptr, eid, x, rw, cb, h1);

    // GAT layer 1
    k_gat_h<32><<<(NN + 255) / 256, 256, 0, stream>>>(h1, g1w, g1as, g1ad, hB, as_v, ad_v);
    k_gat_node<<<(NN * 64 + 255) / 256, 256, 0, stream>>>(rowptr, eid, src, hB, as_v, ad_v, g1b, hC);

    // GAT layer 2
    k_gat_h<64><<<(NN + 255) / 256, 256, 0, stream>>>(hC, g2w, g2as, g2ad, hB, as_v, ad_v);
    k_gat_node<<<(NN * 64 + 255) / 256, 256, 0, stream>>>(rowptr, eid, src, hB, as_v, ad_v, g2b, hD);

    // pool
    k_pool1<<<(NN + 511) / 512, 256, 0, stream>>>(hD, batch, gsum, gcnt);
    k_pool2<<<(NG * 64 + 255) / 256, 256, 0, stream>>>(gsum, gcnt, out);
}